// Round 2
// baseline (814.209 us; speedup 1.0000x reference)
//
#include <hip/hip_runtime.h>

#define ALPHA 0.2f

constexpr int IN  = 64;
constexpr int EIN = 32;
constexpr int H   = 4;
constexpr int D   = 16;
constexpr int HD  = 64;

// ---------------------------------------------------------------------------
// Kernel 1: node transform  ft = x@W + b ; a1 = <ft,attn_l> ; a2 = <ft,attn_r>
// One wave per node; lane c = h*16+d owns output column c.
// ---------------------------------------------------------------------------
__global__ __launch_bounds__(256) void node_kernel(
    const float* __restrict__ x, const float* __restrict__ W,
    const float* __restrict__ b, const float* __restrict__ attn_l,
    const float* __restrict__ attn_r,
    float* __restrict__ ft, float* __restrict__ a1, float* __restrict__ a2,
    int N) {
  __shared__ float Wl[IN * HD];   // 16 KB
  __shared__ float bl[HD], all_[HD], arl[HD];
  int tid = threadIdx.x;
  for (int i = tid; i < IN * HD; i += 256) Wl[i] = W[i];
  if (tid < HD) { bl[tid] = b[tid]; all_[tid] = attn_l[tid]; arl[tid] = attn_r[tid]; }
  __syncthreads();
  int lane = tid & 63, wid = tid >> 6;
  int n = blockIdx.x * 4 + wid;
  if (n >= N) return;
  float xv = x[(size_t)n * IN + lane];
  float acc = bl[lane];
  #pragma unroll
  for (int k = 0; k < IN; ++k) {
    float xk = __shfl(xv, k);
    acc += xk * Wl[k * HD + lane];   // 2-way bank alias: free
  }
  ft[(size_t)n * HD + lane] = acc;
  float p1 = acc * all_[lane];
  float p2 = acc * arl[lane];
  #pragma unroll
  for (int m = 1; m < 16; m <<= 1) {   // reduce over d within each h-group
    p1 += __shfl_xor(p1, m);
    p2 += __shfl_xor(p2, m);
  }
  if ((lane & 15) == 0) {
    a1[n * H + (lane >> 4)] = p1;
    a2[n * H + (lane >> 4)] = p2;
  }
}

// ---------------------------------------------------------------------------
// Kernel 2: per-edge scores = exp(leakyrelu(a1[src] + a2[dst] + e@attn_e))
// Logits are bounded (|a| < ~3 by input scaling) -> skip max-stabilization;
// the softmax ratio cancels the constant exactly.
// ---------------------------------------------------------------------------
__global__ __launch_bounds__(256) void edge_score_kernel(
    const float* __restrict__ e, const int* __restrict__ src,
    const int* __restrict__ dst, const float* __restrict__ attn_e,
    const float* __restrict__ a1, const float* __restrict__ a2,
    float* __restrict__ scores, int E) {
  __shared__ float Ael[EIN * H];   // 512 B
  int tid = threadIdx.x;
  if (tid < EIN * H) Ael[tid] = attn_e[tid];
  __syncthreads();
  int eid = blockIdx.x * 256 + tid;
  if (eid >= E) return;
  const float4* e4 = (const float4*)(e + (size_t)eid * EIN);
  float a3[H] = {0.f, 0.f, 0.f, 0.f};
  #pragma unroll
  for (int j = 0; j < EIN / 4; ++j) {
    float4 v = e4[j];
    const float* vp = &v.x;
    #pragma unroll
    for (int t = 0; t < 4; ++t) {
      float ek = vp[t];
      int k = j * 4 + t;
      #pragma unroll
      for (int h = 0; h < H; ++h) a3[h] += ek * Ael[k * H + h];
    }
  }
  int s = src[eid], d = dst[eid];
  float4 av1 = ((const float4*)a1)[s];   // a1/a2 tables are L2-resident (800KB)
  float4 av2 = ((const float4*)a2)[d];
  const float* p1 = &av1.x;
  const float* p2 = &av2.x;
  float4 o;
  float* op = &o.x;
  #pragma unroll
  for (int h = 0; h < H; ++h) {
    float a = p1[h] + p2[h] + a3[h];
    a = a > 0.f ? a : ALPHA * a;
    op[h] = __expf(a);
  }
  ((float4*)scores)[eid] = o;
}

// ---------------------------------------------------------------------------
// CSR build: count -> exclusive scan -> fill
// ---------------------------------------------------------------------------
__global__ __launch_bounds__(256) void count_kernel(
    const int* __restrict__ dst, int* __restrict__ deg, int E) {
  int i = blockIdx.x * 256 + threadIdx.x;
  if (i < E) atomicAdd(&deg[dst[i]], 1);
}

__global__ __launch_bounds__(1024) void scan_kernel(
    const int* __restrict__ deg, int* __restrict__ rowptr, int N) {
  // single block, 1024 threads: shfl-based chunk scan with running carry
  __shared__ int wsum[16];
  __shared__ int wexcl[16];
  __shared__ int carry;
  int tid = threadIdx.x;
  int lane = tid & 63, wid = tid >> 6;
  if (tid == 0) { carry = 0; rowptr[0] = 0; }
  __syncthreads();
  for (int base = 0; base < N; base += 1024) {
    int i = base + tid;
    int v = (i < N) ? deg[i] : 0;
    int xs = v;
    #pragma unroll
    for (int off = 1; off < 64; off <<= 1) {
      int y = __shfl_up(xs, off);
      if (lane >= off) xs += y;
    }
    if (lane == 63) wsum[wid] = xs;
    __syncthreads();
    if (tid == 0) {
      int run = carry;
      #pragma unroll
      for (int w = 0; w < 16; ++w) { wexcl[w] = run; run += wsum[w]; }
      carry = run;
    }
    __syncthreads();
    if (i < N) rowptr[i + 1] = wexcl[wid] + xs;  // inclusive -> rowptr[i+1]
  }
}

__global__ __launch_bounds__(256) void fill_kernel(
    const int* __restrict__ src, const int* __restrict__ dst,
    const int* __restrict__ rowptr, int* __restrict__ cnt,
    int* __restrict__ csr_eid, int* __restrict__ csr_src, int E) {
  int i = blockIdx.x * 256 + threadIdx.x;
  if (i >= E) return;
  int d = dst[i];
  int pos = rowptr[d] + atomicAdd(&cnt[d], 1);
  csr_eid[pos] = i;
  csr_src[pos] = src[i];
}

// ---------------------------------------------------------------------------
// Kernel 6: per-dst aggregation (one wave per node, zero atomics).
// acc[c] = sum_e score[e,h]*ft[src,c];  z[h] = sum_e score;  esum[k] = sum_e e[e,k]
// epilogue: out = acc/z + esum@We + deg*be   (We applied once per node!)
// ---------------------------------------------------------------------------
__global__ __launch_bounds__(256) void aggregate_kernel(
    const float* __restrict__ e, const float* __restrict__ ft,
    const float* __restrict__ scores, const int* __restrict__ rowptr,
    const int* __restrict__ csr_eid, const int* __restrict__ csr_src,
    const float* __restrict__ We, const float* __restrict__ be,
    float* __restrict__ out, int N) {
  __shared__ float Wel[EIN * HD];   // 8 KB
  __shared__ float bel[HD];
  int tid = threadIdx.x;
  for (int i = tid; i < EIN * HD; i += 256) Wel[i] = We[i];
  if (tid < HD) bel[tid] = be[tid];
  __syncthreads();
  int lane = tid & 63, wid = tid >> 6;
  int n = blockIdx.x * 4 + wid;
  if (n >= N) return;
  int r0 = rowptr[n], r1 = rowptr[n + 1];
  int h = lane >> 4;
  int ke = lane & 31;
  float acc = 0.f, z = 0.f, esum = 0.f;
  for (int i = r0; i < r1; ++i) {
    int eid = csr_eid[i];
    int s = csr_src[i];
    float sc = scores[(size_t)eid * H + h];       // broadcast within h-group
    float fv = ft[(size_t)s * HD + lane];         // 256B coalesced, L2/L3-hit
    float ev = e[(size_t)eid * EIN + ke];         // 128B row gather
    acc += sc * fv;
    z   += sc;
    esum += ev;
  }
  // sum_eft = esum @ We  (esum lives in lanes 0..31, duplicated in 32..63)
  float sacc = 0.f;
  #pragma unroll
  for (int k = 0; k < EIN; ++k) {
    float ek = __shfl(esum, k);
    sacc += ek * Wel[k * HD + lane];
  }
  int degn = r1 - r0;
  float agg = (z > 0.f) ? acc / z : 0.f;   // deg==0 guard (P ~ e^-32, but safe)
  out[(size_t)n * HD + lane] = agg + sacc + (float)degn * bel[lane];
}

// ---------------------------------------------------------------------------
extern "C" void kernel_launch(void* const* d_in, const int* in_sizes, int n_in,
                              void* d_out, int out_size, void* d_ws, size_t ws_size,
                              hipStream_t stream) {
  const float* x      = (const float*)d_in[0];
  const float* e      = (const float*)d_in[1];
  const int*   src    = (const int*)d_in[2];
  const int*   dst    = (const int*)d_in[3];
  const float* W      = (const float*)d_in[4];
  const float* b      = (const float*)d_in[5];
  const float* We     = (const float*)d_in[6];
  const float* be     = (const float*)d_in[7];
  const float* attn_l = (const float*)d_in[8];
  const float* attn_r = (const float*)d_in[9];
  const float* attn_e = (const float*)d_in[10];
  float* out = (float*)d_out;
  int N = in_sizes[0] / IN;
  int E = in_sizes[1] / EIN;

  // workspace carve-up (all 16B-aligned); total ~53.5 MB
  char* w = (char*)d_ws;
  float* ft      = (float*)w; w += (size_t)N * HD * 4;
  float* a1      = (float*)w; w += (size_t)N * H * 4;
  float* a2      = (float*)w; w += (size_t)N * H * 4;
  float* scores  = (float*)w; w += (size_t)E * H * 4;
  int*   deg     = (int*)w;   w += (size_t)N * 4;
  int*   cnt     = (int*)w;   w += (size_t)N * 4;   // contiguous with deg
  int*   rowptr  = (int*)w;   w += (size_t)(N + 4) * 4;
  int*   csr_eid = (int*)w;   w += (size_t)E * 4;
  int*   csr_src = (int*)w;   w += (size_t)E * 4;

  hipMemsetAsync(deg, 0, (size_t)N * 2 * sizeof(int), stream);  // deg + cnt

  node_kernel<<<(N + 3) / 4, 256, 0, stream>>>(x, W, b, attn_l, attn_r, ft, a1, a2, N);
  edge_score_kernel<<<(E + 255) / 256, 256, 0, stream>>>(e, src, dst, attn_e, a1, a2, scores, E);
  count_kernel<<<(E + 255) / 256, 256, 0, stream>>>(dst, deg, E);
  scan_kernel<<<1, 1024, 0, stream>>>(deg, rowptr, N);
  fill_kernel<<<(E + 255) / 256, 256, 0, stream>>>(src, dst, rowptr, cnt, csr_eid, csr_src, E);
  aggregate_kernel<<<(N + 3) / 4, 256, 0, stream>>>(e, ft, scores, rowptr, csr_eid, csr_src, We, be, out, N);
}